// Round 1
// baseline (570.003 us; speedup 1.0000x reference)
//
#include <hip/hip_runtime.h>
#include <stdint.h>

#define NB 4
#define NT 2048
#define ND 1024
#define NH 16
#define NDK 64
#define NTD 3072   // 3*ND

typedef __attribute__((ext_vector_type(8))) short short8;
typedef __attribute__((ext_vector_type(4))) float f32x4;
typedef unsigned short u16;
typedef unsigned int u32;

__device__ __forceinline__ u16 f2bf(float f) {
    u32 u = __builtin_bit_cast(u32, f);
    u += 0x7fffu + ((u >> 16) & 1u);   // RNE
    return (u16)(u >> 16);
}
__device__ __forceinline__ float bf2f(u16 s) {
    u32 u = ((u32)s) << 16;
    return __builtin_bit_cast(float, u);
}

__device__ __forceinline__ void gl_lds16(const u16* g, u16* l) {
    __builtin_amdgcn_global_load_lds(
        (const __attribute__((address_space(1))) u32*)g,
        (__attribute__((address_space(3))) u32*)l, 16, 0, 0);
}

// ---------------- fp32 -> bf16 (RNE) ----------------
__global__ __launch_bounds__(256) void cvt_bf16(const float* __restrict__ in,
                                                u16* __restrict__ out, int n) {
    int i = (blockIdx.x * 256 + threadIdx.x) * 8;
    if (i + 8 > n) return;
    float4 a = *(const float4*)(in + i);
    float4 b = *(const float4*)(in + i + 4);
    short8 r;
    r[0] = (short)f2bf(a.x); r[1] = (short)f2bf(a.y);
    r[2] = (short)f2bf(a.z); r[3] = (short)f2bf(a.w);
    r[4] = (short)f2bf(b.x); r[5] = (short)f2bf(b.y);
    r[6] = (short)f2bf(b.z); r[7] = (short)f2bf(b.w);
    *(short8*)(out + i) = r;
}

// ---------------- bf16 GEMM: C[M,N] = A[M,K] * Bm[N,K]^T ----------------
// 128x128 tile, BK=32, 256 threads = 4 waves (2x2), 4x4 16x16x32 MFMAs/wave.
template <typename OutT>
__global__ __launch_bounds__(256) void gemm_bt(const u16* __restrict__ A,
                                               const u16* __restrict__ Bm,
                                               OutT* __restrict__ C,
                                               int M, int N, int K) {
    __shared__ __align__(16) u16 As[128 * 32];
    __shared__ __align__(16) u16 Bs[128 * 32];
    const int tid  = threadIdx.x;
    const int wave = tid >> 6, lane = tid & 63;
    const int quad = lane >> 4, l16 = lane & 15;
    const int wm = wave >> 1, wn = wave & 1;
    const int row0 = blockIdx.x * 128, col0 = blockIdx.y * 128;

    f32x4 acc[4][4];
#pragma unroll
    for (int i = 0; i < 4; ++i)
#pragma unroll
        for (int j = 0; j < 4; ++j) acc[i][j] = (f32x4){0.f, 0.f, 0.f, 0.f};

    const u16* Ag = A + (size_t)(row0 + (tid >> 2)) * K + ((tid & 3) * 8);
    const u16* Bg = Bm + (size_t)(col0 + (tid >> 2)) * K + ((tid & 3) * 8);
    const size_t stride64 = (size_t)64 * K;
    u16* As0 = As + wave * 512;
    u16* As1 = As + 2048 + wave * 512;
    u16* Bs0 = Bs + wave * 512;
    u16* Bs1 = Bs + 2048 + wave * 512;

    for (int k0 = 0; k0 < K; k0 += 32) {
        gl_lds16(Ag + k0, As0);
        gl_lds16(Ag + k0 + stride64, As1);
        gl_lds16(Bg + k0, Bs0);
        gl_lds16(Bg + k0 + stride64, Bs1);
        __syncthreads();
        short8 af[4], bfr[4];
#pragma unroll
        for (int mi = 0; mi < 4; ++mi)
            af[mi] = *(const short8*)&As[(wm * 64 + mi * 16 + l16) * 32 + quad * 8];
#pragma unroll
        for (int ni = 0; ni < 4; ++ni)
            bfr[ni] = *(const short8*)&Bs[(wn * 64 + ni * 16 + l16) * 32 + quad * 8];
#pragma unroll
        for (int mi = 0; mi < 4; ++mi)
#pragma unroll
            for (int ni = 0; ni < 4; ++ni)
                acc[mi][ni] = __builtin_amdgcn_mfma_f32_16x16x32_bf16(
                    af[mi], bfr[ni], acc[mi][ni], 0, 0, 0);
        __syncthreads();
    }

#pragma unroll
    for (int mi = 0; mi < 4; ++mi) {
#pragma unroll
        for (int ni = 0; ni < 4; ++ni) {
            const int r = row0 + wm * 64 + mi * 16 + quad * 4;
            const int c = col0 + wn * 64 + ni * 16 + l16;
#pragma unroll
            for (int rr = 0; rr < 4; ++rr) {
                float v = acc[mi][ni][rr];
                if constexpr (sizeof(OutT) == 2)
                    C[(size_t)(r + rr) * N + c] = (OutT)f2bf(v);
                else
                    C[(size_t)(r + rr) * N + c] = (OutT)v;
            }
        }
    }
}

// ---------------- flash prefix-LM attention ----------------
// grid: (T/64, B*H), block 256 (4 waves x 16 q-rows). bf16 in/out, fp32 online softmax.
// mask: allowed(q,k) = (q<P) ? (k<P) : (k<=q)
__global__ __launch_bounds__(256) void flash_prefix(const u16* __restrict__ qkv,
                                                    const int* __restrict__ plen,
                                                    u16* __restrict__ attn) {
    __shared__ __align__(16) u16 Pl[4][512];   // per-wave P tile 16x32
    __shared__ __align__(16) u16 Vt[64 * 40];  // V^T tile [d 64][kpos 32], stride 40

    const int tid  = threadIdx.x;
    const int wave = tid >> 6, lane = tid & 63;
    const int quad = lane >> 4, l16 = lane & 15;
    const int bh = blockIdx.y, b = bh >> 4, h = bh & 15;
    const int q0 = blockIdx.x * 64;

    // prefix_lengths: int32 normally (JAX demotes int64); detect int64 layout.
    int P;
    {
        bool is64 = (plen[1] == 0) && (plen[3] == 0);
        P = is64 ? plen[2 * b] : plen[b];
        P = P < 0 ? 0 : (P > NT ? NT : P);
    }

    const u16* Qg = qkv + (size_t)b * NT * NTD + h * NDK;
    const u16* Kg = Qg + ND;
    const u16* Vg = Qg + 2 * ND;

    const int qbase = q0 + wave * 16;

    // Q fragments, pre-scaled by 1/8 (exact in bf16)
    short8 qa[2];
#pragma unroll
    for (int kd = 0; kd < 2; ++kd) {
        short8 t = *(const short8*)(Qg + (size_t)(qbase + l16) * NTD + kd * 32 + quad * 8);
#pragma unroll
        for (int j = 0; j < 8; ++j) {
            float f = bf2f((u16)t[j]) * 0.125f;
            t[j] = (short)f2bf(f);
        }
        qa[kd] = t;
    }

    f32x4 o[4];
#pragma unroll
    for (int nt = 0; nt < 4; ++nt) o[nt] = (f32x4){0.f, 0.f, 0.f, 0.f};
    float m_i[4] = {-1e30f, -1e30f, -1e30f, -1e30f};
    float l_i[4] = {0.f, 0.f, 0.f, 0.f};

    const int kmax = (q0 + 64 > P) ? (q0 + 64) : P;  // block-uniform
    const int vr = tid >> 3;          // 0..31 (key row within tile)
    const int vc0 = (tid & 7) * 8;    // 0..56 (d col)

    for (int k0 = 0; k0 < kmax; k0 += 32) {
        // stage V transposed: Vt[d][kpos]
        {
            short8 vv = *(const short8*)(Vg + (size_t)(k0 + vr) * NTD + vc0);
#pragma unroll
            for (int j = 0; j < 8; ++j) Vt[(vc0 + j) * 40 + vr] = (u16)vv[j];
        }
        // S = Q K^T (pre-scaled)
        f32x4 s[2];
#pragma unroll
        for (int ni = 0; ni < 2; ++ni) {
            s[ni] = (f32x4){0.f, 0.f, 0.f, 0.f};
#pragma unroll
            for (int kd = 0; kd < 2; ++kd) {
                short8 kb = *(const short8*)(Kg + (size_t)(k0 + ni * 16 + l16) * NTD + kd * 32 + quad * 8);
                s[ni] = __builtin_amdgcn_mfma_f32_16x16x32_bf16(qa[kd], kb, s[ni], 0, 0, 0);
            }
        }
        // mask
#pragma unroll
        for (int ni = 0; ni < 2; ++ni) {
            const int kpos = k0 + ni * 16 + l16;
#pragma unroll
            for (int rr = 0; rr < 4; ++rr) {
                const int qrow = qbase + quad * 4 + rr;
                const bool ok = (qrow < P) ? (kpos < P) : (kpos <= qrow);
                if (!ok) s[ni][rr] = -1e30f;
            }
        }
        // online softmax update
        float alpha[4];
#pragma unroll
        for (int rr = 0; rr < 4; ++rr) {
            float mr = fmaxf(s[0][rr], s[1][rr]);
            mr = fmaxf(mr, __shfl_xor(mr, 1));
            mr = fmaxf(mr, __shfl_xor(mr, 2));
            mr = fmaxf(mr, __shfl_xor(mr, 4));
            mr = fmaxf(mr, __shfl_xor(mr, 8));
            const float mn = fmaxf(m_i[rr], mr);
            alpha[rr] = __expf(m_i[rr] - mn);
            m_i[rr] = mn;
            const float p0 = __expf(s[0][rr] - mn);
            const float p1 = __expf(s[1][rr] - mn);
            s[0][rr] = p0; s[1][rr] = p1;
            float rs = p0 + p1;
            rs += __shfl_xor(rs, 1);
            rs += __shfl_xor(rs, 2);
            rs += __shfl_xor(rs, 4);
            rs += __shfl_xor(rs, 8);
            l_i[rr] = l_i[rr] * alpha[rr] + rs;
        }
#pragma unroll
        for (int nt = 0; nt < 4; ++nt)
#pragma unroll
            for (int rr = 0; rr < 4; ++rr) o[nt][rr] *= alpha[rr];
        // P -> LDS (C-layout -> A-layout round trip)
        u16* Pw = Pl[wave];
#pragma unroll
        for (int ni = 0; ni < 2; ++ni)
#pragma unroll
            for (int rr = 0; rr < 4; ++rr)
                Pw[(quad * 4 + rr) * 32 + ni * 16 + l16] = f2bf(s[ni][rr]);
        __syncthreads();   // V tile loaded + P visible
        const short8 pa = *(const short8*)&Pw[l16 * 32 + quad * 8];
#pragma unroll
        for (int nt = 0; nt < 4; ++nt) {
            const short8 vb = *(const short8*)&Vt[(nt * 16 + l16) * 40 + quad * 8];
            o[nt] = __builtin_amdgcn_mfma_f32_16x16x32_bf16(pa, vb, o[nt], 0, 0, 0);
        }
        __syncthreads();   // reads done before next stage overwrites Vt
    }

    // epilogue: normalize, store bf16
#pragma unroll
    for (int rr = 0; rr < 4; ++rr) {
        const float inv = 1.0f / l_i[rr];
        const size_t rowoff = (size_t)(b * NT + qbase + quad * 4 + rr) * ND + h * NDK;
#pragma unroll
        for (int nt = 0; nt < 4; ++nt)
            attn[rowoff + nt * 16 + l16] = f2bf(o[nt][rr] * inv);
    }
}

extern "C" void kernel_launch(void* const* d_in, const int* in_sizes, int n_in,
                              void* d_out, int out_size, void* d_ws, size_t ws_size,
                              hipStream_t stream) {
    const float* x    = (const float*)d_in[0];
    const int*   plen = (const int*)d_in[1];
    const float* wqkv = (const float*)d_in[2];
    const float* wo   = (const float*)d_in[3];
    float* out = (float*)d_out;

    char* ws = (char*)d_ws;
    u16* xb   = (u16*)(ws);                  // 8192*1024*2   = 16,777,216
    u16* wqb  = (u16*)(ws + 16777216);       // 3072*1024*2   =  6,291,456
    u16* wob  = (u16*)(ws + 23068672);       // 1024*1024*2   =  2,097,152
    u16* qkv  = (u16*)(ws + 25165824);       // 8192*3072*2   = 50,331,648
    u16* attn = (u16*)(ws + 75497472);       // 8192*1024*2   = 16,777,216
    // total 92,274,688 bytes

    cvt_bf16<<<4096, 256, 0, stream>>>(x, xb, NB * NT * ND);
    cvt_bf16<<<1536, 256, 0, stream>>>(wqkv, wqb, 3 * ND * ND);
    cvt_bf16<<<512, 256, 0, stream>>>(wo, wob, ND * ND);

    // QKV = x @ W_qkv^T  (M=8192, N=3072, K=1024)
    gemm_bt<u16><<<dim3(64, 24), 256, 0, stream>>>(xb, wqb, qkv, NB * NT, 3 * ND, ND);

    // attention
    flash_prefix<<<dim3(NT / 64, NB * NH), 256, 0, stream>>>(qkv, plen, attn);

    // out = attn @ W_o^T  (M=8192, N=1024, K=1024)
    gemm_bt<float><<<dim3(64, 8), 256, 0, stream>>>(attn, wob, out, NB * NT, ND, ND);
}

// Round 2
// 365.757 us; speedup vs baseline: 1.5584x; 1.5584x over previous
//
#include <hip/hip_runtime.h>
#include <stdint.h>

#define NB 4
#define NT 2048
#define ND 1024
#define NH 16
#define NDK 64
#define NTD 3072   // 3*ND

typedef __attribute__((ext_vector_type(8))) short short8;
typedef __attribute__((ext_vector_type(4))) float f32x4;
typedef unsigned short u16;
typedef unsigned int u32;

__device__ __forceinline__ u16 f2bf(float f) {
    u32 u = __builtin_bit_cast(u32, f);
    u += 0x7fffu + ((u >> 16) & 1u);   // RNE
    return (u16)(u >> 16);
}
__device__ __forceinline__ float bf2f(u16 s) {
    u32 u = ((u32)s) << 16;
    return __builtin_bit_cast(float, u);
}

__device__ __forceinline__ void gl_lds16(const u16* g, u16* l) {
    __builtin_amdgcn_global_load_lds(
        (const __attribute__((address_space(1))) u32*)g,
        (__attribute__((address_space(3))) u32*)l, 16, 0, 0);
}

// XOR-swizzled tile index: rows of 32 u16 (64B), 4 atoms of 8 u16 (16B).
// atom ^= ((row>>1)^(row>>3))&3 -> b128 reads conflict-free, scalar
// transpose writes 2-way (free, m136).
__device__ __forceinline__ int swz(int row, int col) {
    return row * 32 + ((((col >> 3) ^ (row >> 1) ^ (row >> 3)) & 3) << 3) + (col & 7);
}

// ---------------- fp32 -> bf16 (RNE) ----------------
__global__ __launch_bounds__(256) void cvt_bf16(const float* __restrict__ in,
                                                u16* __restrict__ out, int n) {
    int i = (blockIdx.x * 256 + threadIdx.x) * 8;
    if (i + 8 > n) return;
    float4 a = *(const float4*)(in + i);
    float4 b = *(const float4*)(in + i + 4);
    short8 r;
    r[0] = (short)f2bf(a.x); r[1] = (short)f2bf(a.y);
    r[2] = (short)f2bf(a.z); r[3] = (short)f2bf(a.w);
    r[4] = (short)f2bf(b.x); r[5] = (short)f2bf(b.y);
    r[6] = (short)f2bf(b.z); r[7] = (short)f2bf(b.w);
    *(short8*)(out + i) = r;
}

// ---------------- bf16 GEMM: C[M,N] = A[M,K] * Bm[N,K]^T ----------------
template <typename OutT>
__global__ __launch_bounds__(256) void gemm_bt(const u16* __restrict__ A,
                                               const u16* __restrict__ Bm,
                                               OutT* __restrict__ C,
                                               int M, int N, int K) {
    __shared__ __align__(16) u16 As[128 * 32];
    __shared__ __align__(16) u16 Bs[128 * 32];
    const int tid  = threadIdx.x;
    const int wave = tid >> 6, lane = tid & 63;
    const int quad = lane >> 4, l16 = lane & 15;
    const int wm = wave >> 1, wn = wave & 1;
    const int row0 = blockIdx.x * 128, col0 = blockIdx.y * 128;

    f32x4 acc[4][4];
#pragma unroll
    for (int i = 0; i < 4; ++i)
#pragma unroll
        for (int j = 0; j < 4; ++j) acc[i][j] = (f32x4){0.f, 0.f, 0.f, 0.f};

    const u16* Ag = A + (size_t)(row0 + (tid >> 2)) * K + ((tid & 3) * 8);
    const u16* Bg = Bm + (size_t)(col0 + (tid >> 2)) * K + ((tid & 3) * 8);
    const size_t stride64 = (size_t)64 * K;
    u16* As0 = As + wave * 512;
    u16* As1 = As + 2048 + wave * 512;
    u16* Bs0 = Bs + wave * 512;
    u16* Bs1 = Bs + 2048 + wave * 512;

    for (int k0 = 0; k0 < K; k0 += 32) {
        gl_lds16(Ag + k0, As0);
        gl_lds16(Ag + k0 + stride64, As1);
        gl_lds16(Bg + k0, Bs0);
        gl_lds16(Bg + k0 + stride64, Bs1);
        __syncthreads();
        short8 af[4], bfr[4];
#pragma unroll
        for (int mi = 0; mi < 4; ++mi)
            af[mi] = *(const short8*)&As[(wm * 64 + mi * 16 + l16) * 32 + quad * 8];
#pragma unroll
        for (int ni = 0; ni < 4; ++ni)
            bfr[ni] = *(const short8*)&Bs[(wn * 64 + ni * 16 + l16) * 32 + quad * 8];
#pragma unroll
        for (int mi = 0; mi < 4; ++mi)
#pragma unroll
            for (int ni = 0; ni < 4; ++ni)
                acc[mi][ni] = __builtin_amdgcn_mfma_f32_16x16x32_bf16(
                    af[mi], bfr[ni], acc[mi][ni], 0, 0, 0);
        __syncthreads();
    }

#pragma unroll
    for (int mi = 0; mi < 4; ++mi) {
#pragma unroll
        for (int ni = 0; ni < 4; ++ni) {
            const int r = row0 + wm * 64 + mi * 16 + quad * 4;
            const int c = col0 + wn * 64 + ni * 16 + l16;
#pragma unroll
            for (int rr = 0; rr < 4; ++rr) {
                float v = acc[mi][ni][rr];
                if constexpr (sizeof(OutT) == 2)
                    C[(size_t)(r + rr) * N + c] = (OutT)f2bf(v);
                else
                    C[(size_t)(r + rr) * N + c] = (OutT)v;
            }
        }
    }
}

// ---------------- flash prefix-LM attention (v2) ----------------
// grid: (B*H, 16). Block handles q-tiles ip and 31-ip (uniform work).
// Constant-max softmax in exp2 domain; per-lane l, epilogue reduction.
// Swizzled LDS for V-transpose and P round-trip; double-buffered V,
// one barrier per 32-key step.
__global__ __launch_bounds__(256) void flash_prefix(const u16* __restrict__ qkv,
                                                    const int* __restrict__ plen,
                                                    u16* __restrict__ attn) {
    __shared__ __align__(16) u16 Vt[2][2048];  // [buf][d 64][kpos 32] swizzled
    __shared__ __align__(16) u16 Pl[4 * 512];  // per-wave 16x32 swizzled

    const int tid  = threadIdx.x;
    const int wave = tid >> 6, lane = tid & 63;
    const int quad = lane >> 4, l16 = lane & 15;
    const int bh = blockIdx.x, b = bh >> 4, h = bh & 15;
    const int ip = blockIdx.y;

    int P;
    {
        bool is64 = (plen[1] == 0) && (plen[3] == 0);
        P = is64 ? plen[2 * b] : plen[b];
        P = P < 0 ? 0 : (P > NT ? NT : P);
    }

    const u16* Qg = qkv + (size_t)b * NT * NTD + h * NDK;
    const u16* Kg = Qg + ND;
    const u16* Vg = Qg + 2 * ND;

    const int vr = tid >> 3, g = tid & 7;   // V staging: kpos row, d-group
    u16* Pw = Pl + wave * 512;

    const float C = 23.0831207f;           // 16*log2(e); arbitrary, cancels in o/l
    const float QSCALE = 0.18033688f;      // log2(e)/8
    int buf = 0;

    for (int t = 0; t < 2; ++t) {
        const int q0 = (t == 0 ? ip : 31 - ip) * 64;
        const int qbase = q0 + wave * 16;

        // Q fragments pre-scaled into exp2 domain
        short8 qa[2];
#pragma unroll
        for (int kd = 0; kd < 2; ++kd) {
            short8 tq = *(const short8*)(Qg + (size_t)(qbase + l16) * NTD + kd * 32 + quad * 8);
#pragma unroll
            for (int j = 0; j < 8; ++j)
                tq[j] = (short)f2bf(bf2f((u16)tq[j]) * QSCALE);
            qa[kd] = tq;
        }

        f32x4 o[4];
#pragma unroll
        for (int nt = 0; nt < 4; ++nt) o[nt] = (f32x4){0.f, 0.f, 0.f, 0.f};
        float lp[4] = {0.f, 0.f, 0.f, 0.f};

        int kl[4];
#pragma unroll
        for (int rr = 0; rr < 4; ++rr) {
            const int qrow = qbase + quad * 4 + rr;
            kl[rr] = (qrow < P) ? P : (qrow + 1);
        }
        const int klmin = (qbase < P) ? P : (qbase + 1);  // wave-uniform
        const int kmax = (q0 + 64 > P) ? (q0 + 64) : P;   // block-uniform

        for (int k0 = 0; k0 < kmax; k0 += 32) {
            // stage V transposed (swizzled, conflict-free-ish)
            u16* Vb = Vt[buf];
            {
                short8 vv = *(const short8*)(Vg + (size_t)(k0 + vr) * NTD + g * 8);
#pragma unroll
                for (int r = 0; r < 8; ++r)
                    Vb[swz(g * 8 + r, vr)] = (u16)vv[r];
            }
            __syncthreads();

            // S = Q K^T (exp2-domain, pre-scaled)
            f32x4 s[2];
#pragma unroll
            for (int ni = 0; ni < 2; ++ni) {
                s[ni] = (f32x4){0.f, 0.f, 0.f, 0.f};
#pragma unroll
                for (int kd = 0; kd < 2; ++kd) {
                    short8 kb = *(const short8*)(Kg + (size_t)(k0 + ni * 16 + l16) * NTD + kd * 32 + quad * 8);
                    s[ni] = __builtin_amdgcn_mfma_f32_16x16x32_bf16(qa[kd], kb, s[ni], 0, 0, 0);
                }
            }

            // softmax numerator: p = 2^(s - C); per-lane l accumulation
            const bool full = (k0 + 32 <= klmin);   // wave-uniform
#pragma unroll
            for (int ni = 0; ni < 2; ++ni) {
#pragma unroll
                for (int rr = 0; rr < 4; ++rr) {
                    float sv = s[ni][rr];
                    if (!full) {
                        const int kpos = k0 + ni * 16 + l16;
                        sv = (kpos < kl[rr]) ? sv : -1e30f;
                    }
                    const float p = exp2f(sv - C);
                    lp[rr] += p;
                    const u32 u = __builtin_bit_cast(u32, p);
                    Pw[swz(quad * 4 + rr, ni * 16 + l16)] = (u16)((u + 0x8000u) >> 16);
                }
            }

            // PV
            const short8 pa = *(const short8*)&Pw[swz(l16, quad * 8)];
#pragma unroll
            for (int nt = 0; nt < 4; ++nt) {
                const short8 vb = *(const short8*)&Vb[swz(nt * 16 + l16, quad * 8)];
                o[nt] = __builtin_amdgcn_mfma_f32_16x16x32_bf16(pa, vb, o[nt], 0, 0, 0);
            }
            buf ^= 1;
        }

        // epilogue: reduce l across the 16-lane row group, normalize, store
#pragma unroll
        for (int rr = 0; rr < 4; ++rr) {
            float l = lp[rr];
            l += __shfl_xor(l, 1);
            l += __shfl_xor(l, 2);
            l += __shfl_xor(l, 4);
            l += __shfl_xor(l, 8);
            const float inv = 1.0f / l;
            const size_t rowoff = (size_t)(b * NT + qbase + quad * 4 + rr) * ND + h * NDK;
#pragma unroll
            for (int nt = 0; nt < 4; ++nt)
                attn[rowoff + nt * 16 + l16] = f2bf(o[nt][rr] * inv);
        }
    }
}

extern "C" void kernel_launch(void* const* d_in, const int* in_sizes, int n_in,
                              void* d_out, int out_size, void* d_ws, size_t ws_size,
                              hipStream_t stream) {
    const float* x    = (const float*)d_in[0];
    const int*   plen = (const int*)d_in[1];
    const float* wqkv = (const float*)d_in[2];
    const float* wo   = (const float*)d_in[3];
    float* out = (float*)d_out;

    char* ws = (char*)d_ws;
    u16* xb   = (u16*)(ws);                  // 16,777,216
    u16* wqb  = (u16*)(ws + 16777216);       //  6,291,456
    u16* wob  = (u16*)(ws + 23068672);       //  2,097,152
    u16* qkv  = (u16*)(ws + 25165824);       // 50,331,648
    u16* attn = (u16*)(ws + 75497472);       // 16,777,216

    cvt_bf16<<<4096, 256, 0, stream>>>(x, xb, NB * NT * ND);
    cvt_bf16<<<1536, 256, 0, stream>>>(wqkv, wqb, 3 * ND * ND);
    cvt_bf16<<<512, 256, 0, stream>>>(wo, wob, ND * ND);

    // QKV = x @ W_qkv^T  (M=8192, N=3072, K=1024)
    gemm_bt<u16><<<dim3(64, 24), 256, 0, stream>>>(xb, wqb, qkv, NB * NT, 3 * ND, ND);

    // attention
    flash_prefix<<<dim3(NB * NH, 16), 256, 0, stream>>>(qkv, plen, attn);

    // out = attn @ W_o^T  (M=8192, N=1024, K=1024)
    gemm_bt<float><<<dim3(64, 8), 256, 0, stream>>>(attn, wob, out, NB * NT, ND, ND);
}